// Round 8
// baseline (269.184 us; speedup 1.0000x reference)
//
#include <hip/hip_runtime.h>

#define N_NODES 50000
#define D 128
#define N_EDGES 400000
#define NCHUNKS ((N_NODES + 255) / 256)   // 196
#define NBLK64 ((N_NODES + 63) / 64)      // 782
#define W_FRAG_SHORTS 16384               // 32 frags * 64 lanes * 8 bf16 per weight

#define CVT_BLOCKS 3125                   // 6.4M elems / 2048 per block
#define MW_BLOCKS  64                     // 8 weights * 8 slot-blocks
#define HIST_BLOCKS ((N_EDGES + 255) / 256)   // 1563
#define PREP_BLOCKS (CVT_BLOCKS + MW_BLOCKS + HIST_BLOCKS)

typedef short s8v  __attribute__((ext_vector_type(8)));   // 8 bf16 (4 VGPRs)
typedef float f4v  __attribute__((ext_vector_type(4)));   // MFMA accumulator

__device__ __forceinline__ unsigned int f2bf(float f) {
    unsigned int u = __float_as_uint(f);
    u += 0x7FFFu + ((u >> 16) & 1u);
    return u >> 16;
}
__device__ __forceinline__ unsigned int packbf(float a, float b) {
    return (f2bf(b) << 16) | f2bf(a);
}
__device__ __forceinline__ float bflo(unsigned int u) { return __uint_as_float(u << 16); }
__device__ __forceinline__ float bfhi(unsigned int u) { return __uint_as_float(u & 0xFFFF0000u); }
__device__ __forceinline__ float sigm(float x) {
    return __builtin_amdgcn_rcpf(1.f + __expf(-x));   // v_rcp_f32, ~1 ulp
}

// ---------------------------------------------------------------------------
// Fused prep: [0,CVT) x->bf16 | [CVT,CVT+MW) weight frags | rest: tgt histogram.
// ---------------------------------------------------------------------------
__global__ __launch_bounds__(256)
void prep_all(const float* __restrict__ X, short* __restrict__ Xb,
              const float* __restrict__ W0, const float* __restrict__ W1,
              const float* __restrict__ W2, const float* __restrict__ W3,
              const float* __restrict__ W4, const float* __restrict__ W5,
              const float* __restrict__ W6, const float* __restrict__ W7,
              short* __restrict__ Wt,
              const int* __restrict__ tgt, int* __restrict__ counts)
{
    const int b = blockIdx.x;
    if (b < CVT_BLOCKS) {
        const size_t i = ((size_t)b * 256 + threadIdx.x) * 8;
        float4 a0 = *(const float4*)(X + i);
        float4 a1 = *(const float4*)(X + i + 4);
        s8v v;
        v[0] = (short)f2bf(a0.x); v[1] = (short)f2bf(a0.y);
        v[2] = (short)f2bf(a0.z); v[3] = (short)f2bf(a0.w);
        v[4] = (short)f2bf(a1.x); v[5] = (short)f2bf(a1.y);
        v[6] = (short)f2bf(a1.z); v[7] = (short)f2bf(a1.w);
        *(s8v*)(Xb + i) = v;
    } else if (b < CVT_BLOCKS + MW_BLOCKS) {
        const int bb   = b - CVT_BLOCKS;
        const int wsel = bb >> 3;
        const float* W = (wsel == 0) ? W0 : (wsel == 1) ? W1 : (wsel == 2) ? W2 :
                         (wsel == 3) ? W3 : (wsel == 4) ? W4 : (wsel == 5) ? W5 :
                         (wsel == 6) ? W6 : W7;
        const int slot = (bb & 7) * 256 + threadIdx.x;
        const int frag = slot >> 6;
        const int lane = slot & 63;
        const int n    = (frag >> 2) * 16 + (lane & 15);
        const int kc   = frag & 3;
        const int quad = lane >> 4;
        const int k0   = kc * 32 + quad * 8;
        s8v v;
#pragma unroll
        for (int j = 0; j < 8; ++j)
            v[j] = (short)f2bf(W[(size_t)(k0 + j) * D + n]);
        *(s8v*)(Wt + (size_t)wsel * W_FRAG_SHORTS + (size_t)slot * 8) = v;
    } else {
        const int e = (b - CVT_BLOCKS - MW_BLOCKS) * 256 + threadIdx.x;
        if (e < N_EDGES) atomicAdd(&counts[tgt[e]], 1);
    }
}

// ---------------------------------------------------------------------------
// Single-kernel CSR offset build. 196 blocks (all trivially co-resident on an
// idle 256-CU device): local inclusive scan of this chunk's 256 counts,
// publish chunk total (release), spin on done-counter (acquire), then block-
// reduce the preceding chunk totals for the base. off[N] is the constant E.
// ---------------------------------------------------------------------------
__global__ __launch_bounds__(256)
void csr_scan(const int* __restrict__ counts, int* __restrict__ off,
              int* __restrict__ cursor, int* __restrict__ done_ctr,
              int* __restrict__ chunk_sum)
{
    __shared__ int s[256];
    const int b = blockIdx.x, t = threadIdx.x;
    const int i = b * 256 + t;
    const int v = (i < N_NODES) ? counts[i] : 0;
    s[t] = v;
    __syncthreads();
    for (int d = 1; d < 256; d <<= 1) {
        int tt = (t >= d) ? s[t - d] : 0;
        __syncthreads();
        s[t] += tt;
        __syncthreads();
    }
    const int incl = s[t];

    if (t == 255) {
        __hip_atomic_store(&chunk_sum[b], incl, __ATOMIC_RELAXED, __HIP_MEMORY_SCOPE_AGENT);
        __hip_atomic_fetch_add(done_ctr, 1, __ATOMIC_RELEASE, __HIP_MEMORY_SCOPE_AGENT);
    }
    if (t == 0) {
        while (__hip_atomic_load(done_ctr, __ATOMIC_ACQUIRE, __HIP_MEMORY_SCOPE_AGENT) < NCHUNKS)
            __builtin_amdgcn_s_sleep(8);
    }
    __syncthreads();

    // base = sum of chunk totals before this chunk
    const int pv = (t < b) ? __hip_atomic_load(&chunk_sum[t], __ATOMIC_RELAXED,
                                               __HIP_MEMORY_SCOPE_AGENT) : 0;
    __syncthreads();   // incl is in registers; s[] reusable
    s[t] = pv;
    __syncthreads();
    for (int d = 128; d > 0; d >>= 1) {
        if (t < d) s[t] += s[t + d];
        __syncthreads();
    }
    const int base = s[0];

    if (i < N_NODES) {
        const int excl = base + incl - v;
        off[i]    = excl;
        cursor[i] = excl;
    }
    if (b == 0 && t == 0) off[N_NODES] = N_EDGES;
}

// ---------------------------------------------------------------------------
// GEMM tile (device fn): 64 rows x 128 cols x 4 projections (verified in R6).
// ---------------------------------------------------------------------------
__device__ __forceinline__
void gemm_tile(int m0, const short* __restrict__ Xb, const short* __restrict__ WtL,
               const float* __restrict__ bias, short* __restrict__ Kb,
               unsigned int* __restrict__ QV, float* __restrict__ Agg,
               short* As, short* Bs, float* biasS)
{
    const int tid  = threadIdx.x;
    const int lane = tid & 63;
    const int w    = tid >> 6;
    const int wr   = w & 1;
    const int wc   = w >> 1;

    if (tid < 128) biasS[tid] = bias[tid];

#pragma unroll
    for (int i = 0; i < 4; ++i) {
        const int m   = (tid >> 4) + 16 * i;
        const int oct = tid & 15;
        const int row = m0 + m;
        s8v v = (s8v){0, 0, 0, 0, 0, 0, 0, 0};
        if (row < N_NODES) v = *(const s8v*)(Xb + (size_t)row * D + oct * 8);
        const int kc = oct >> 2, quad = oct & 3;
        const int frag = (m >> 4) * 4 + kc;
        const int slot = ((m & 15) + 16 * quad) ^ (kc << 1);
        *(s8v*)&As[frag * 512 + slot * 8] = v;
    }

    float* Cs = (float*)Bs;

    for (int sel = 0; sel < 4; ++sel) {
        __syncthreads();

        const short* Wf = WtL + (size_t)sel * W_FRAG_SHORTS;
#pragma unroll
        for (int j = 0; j < 8; ++j) {
            const int chunk = tid + 256 * j;
            __builtin_amdgcn_global_load_lds(
                (const __attribute__((address_space(1))) unsigned int*)(Wf + chunk * 8),
                (__attribute__((address_space(3))) unsigned int*)(&Bs[(chunk & ~63) * 8]),
                16, 0, 0);
        }
        __syncthreads();

        f4v acc[2][4];
#pragma unroll
        for (int mt = 0; mt < 2; ++mt)
#pragma unroll
            for (int nt = 0; nt < 4; ++nt)
                acc[mt][nt] = (f4v){0.f, 0.f, 0.f, 0.f};

#pragma unroll
        for (int kc = 0; kc < 4; ++kc) {
            const int sl = (lane ^ (kc << 1)) * 8;
            s8v a0 = *(const s8v*)&As[((2 * wr + 0) * 4 + kc) * 512 + sl];
            s8v a1 = *(const s8v*)&As[((2 * wr + 1) * 4 + kc) * 512 + sl];
#pragma unroll
            for (int nt = 0; nt < 4; ++nt) {
                s8v b = *(const s8v*)&Bs[((4 * wc + nt) * 4 + kc) * 512 + lane * 8];
                acc[0][nt] = __builtin_amdgcn_mfma_f32_16x16x32_bf16(a0, b, acc[0][nt], 0, 0, 0);
                acc[1][nt] = __builtin_amdgcn_mfma_f32_16x16x32_bf16(a1, b, acc[1][nt], 0, 0, 0);
            }
        }
        __syncthreads();

#pragma unroll
        for (int mt = 0; mt < 2; ++mt) {
            const int r0 = wr * 32 + mt * 16 + (lane >> 4) * 4;
#pragma unroll
            for (int nt = 0; nt < 4; ++nt) {
                const int col = wc * 64 + nt * 16 + (lane & 15);
                const int g = col >> 2, jj = col & 3;
#pragma unroll
                for (int i = 0; i < 4; ++i) {
                    const int row = r0 + i;
                    const int gs  = g ^ (((row >> 2) & 3) << 2);
                    Cs[row * 128 + gs * 4 + jj] = acc[mt][nt][i];
                }
            }
        }
        __syncthreads();

#pragma unroll
        for (int j = 0; j < 8; ++j) {
            const int c    = tid + 256 * j;
            const int row  = c >> 5;
            const int gg   = c & 31;
            const int gs   = gg ^ (((row >> 2) & 3) << 2);
            const f4v vv   = *(const f4v*)&Cs[row * 128 + gs * 4];
            const int grow = m0 + row;
            if (grow >= N_NODES) continue;
            if (sel == 3) {
                const float4 bv = *(const float4*)&biasS[gg * 4];
                float4 o = make_float4(vv[0] + bv.x, vv[1] + bv.y,
                                       vv[2] + bv.z, vv[3] + bv.w);
                *(float4*)&Agg[(size_t)grow * D + gg * 4] = o;
            } else {
                const unsigned int p0 = packbf(vv[0], vv[1]);
                const unsigned int p1 = packbf(vv[2], vv[3]);
                if (sel == 0) {
                    uint2* kp = (uint2*)((unsigned int*)Kb + (size_t)grow * 64 + gg * 2);
                    *kp = make_uint2(p0, p1);
                } else {
                    unsigned int* rowp = QV + (size_t)grow * 128 + gg * 4 + (sel == 2 ? 1 : 0);
                    rowp[0] = p0; rowp[2] = p1;
                }
            }
        }
    }
}

// ---------------------------------------------------------------------------
// Layer-1 GEMM with the edge scatter fused in as extra blocks (independent
// work; its atomic latency hides under gemm compute). agg1 consumer is the
// next dispatch, so both must finish here — they do.
// ---------------------------------------------------------------------------
__global__ __launch_bounds__(256)
void gemm1_scatter(const short* __restrict__ Xb, const short* __restrict__ WtL,
                   const float* __restrict__ bias,
                   short* __restrict__ Kb, unsigned int* __restrict__ QV,
                   float* __restrict__ Agg,
                   const int* __restrict__ src, const int* __restrict__ tgt,
                   int* __restrict__ cursor, int* __restrict__ es)
{
    __shared__ __align__(16) short As[8192];    // 16 KB
    __shared__ __align__(16) short Bs[16384];   // 32 KB (doubles as Cs fp32)
    __shared__ __align__(16) float biasS[128];

    if (blockIdx.x < NBLK64) {
        gemm_tile(blockIdx.x * 64, Xb, WtL, bias, Kb, QV, Agg, As, Bs, biasS);
    } else {
        const int e = (blockIdx.x - NBLK64) * 256 + threadIdx.x;
        if (e < N_EDGES) {
            int pos = atomicAdd(&cursor[tgt[e]], 1);
            es[pos] = src[e];
        }
    }
}

__global__ __launch_bounds__(256)
void gemm_all(const short* __restrict__ Xb, const short* __restrict__ WtL,
              const float* __restrict__ bias,
              short* __restrict__ Kb, unsigned int* __restrict__ QV,
              float* __restrict__ Agg)
{
    __shared__ __align__(16) short As[8192];
    __shared__ __align__(16) short Bs[16384];
    __shared__ __align__(16) float biasS[128];
    gemm_tile(blockIdx.x * 64, Xb, WtL, bias, Kb, QV, Agg, As, Bs, biasS);
}

// ---------------------------------------------------------------------------
// Atomic-free per-node aggregation (R6-verified): one wave per node, 4 edges
// in flight, one uint2 gather per edge per lane.
// ---------------------------------------------------------------------------
template<bool FIRST>
__global__ __launch_bounds__(256)
void node_agg(const int* __restrict__ off, const int* __restrict__ es,
              const short* __restrict__ K, const unsigned int* __restrict__ QV,
              const float* __restrict__ Skip, float* __restrict__ OutF,
              unsigned int* __restrict__ Hb)
{
    const int lane = threadIdx.x & 63;
    const int t    = __builtin_amdgcn_readfirstlane(blockIdx.x * 4 + (threadIdx.x >> 6));

    const unsigned int ku = ((const unsigned int*)K)[(size_t)t * 64 + lane];
    const float kx = bflo(ku), ky = bfhi(ku);
    const float2 sk = ((const float2*)Skip)[(size_t)t * 64 + lane];

    float ax = 0.f, ay = 0.f, bx = 0.f, by = 0.f;
    float cx = 0.f, cy = 0.f, dx = 0.f, dy = 0.f;
    const int e0 = __builtin_amdgcn_readfirstlane(off[t]);
    const int e1 = __builtin_amdgcn_readfirstlane(off[t + 1]);

    int e = e0;
    for (; e + 4 <= e1; e += 4) {
        const int s0 = __builtin_amdgcn_readfirstlane(es[e]);
        const int s1 = __builtin_amdgcn_readfirstlane(es[e + 1]);
        const int s2 = __builtin_amdgcn_readfirstlane(es[e + 2]);
        const int s3 = __builtin_amdgcn_readfirstlane(es[e + 3]);
        const uint2 qv0 = ((const uint2*)(QV + (size_t)s0 * 128))[lane];
        const uint2 qv1 = ((const uint2*)(QV + (size_t)s1 * 128))[lane];
        const uint2 qv2 = ((const uint2*)(QV + (size_t)s2 * 128))[lane];
        const uint2 qv3 = ((const uint2*)(QV + (size_t)s3 * 128))[lane];
        ax += bflo(qv0.y) * sigm(kx + bflo(qv0.x));
        ay += bfhi(qv0.y) * sigm(ky + bfhi(qv0.x));
        bx += bflo(qv1.y) * sigm(kx + bflo(qv1.x));
        by += bfhi(qv1.y) * sigm(ky + bfhi(qv1.x));
        cx += bflo(qv2.y) * sigm(kx + bflo(qv2.x));
        cy += bfhi(qv2.y) * sigm(ky + bfhi(qv2.x));
        dx += bflo(qv3.y) * sigm(kx + bflo(qv3.x));
        dy += bfhi(qv3.y) * sigm(ky + bfhi(qv3.x));
    }
    for (; e < e1; ++e) {
        const int s0 = __builtin_amdgcn_readfirstlane(es[e]);
        const uint2 qv0 = ((const uint2*)(QV + (size_t)s0 * 128))[lane];
        ax += bflo(qv0.y) * sigm(kx + bflo(qv0.x));
        ay += bfhi(qv0.y) * sigm(ky + bfhi(qv0.x));
    }

    const float rx = sk.x + (ax + bx) + (cx + dx);
    const float ry = sk.y + (ay + by) + (cy + dy);

    if (FIRST) {
        Hb[(size_t)t * 64 + lane] = packbf(fmaxf(rx, 0.f), fmaxf(ry, 0.f));
    } else {
        ((float2*)OutF)[(size_t)t * 64 + lane] = make_float2(rx, ry);
    }
}

extern "C" void kernel_launch(void* const* d_in, const int* in_sizes, int n_in,
                              void* d_out, int out_size, void* d_ws, size_t ws_size,
                              hipStream_t stream)
{
    const float* x   = (const float*)d_in[0];
    const int*   ei  = (const int*)d_in[1];
    const float* Wk1 = (const float*)d_in[2];
    const float* Wq1 = (const float*)d_in[3];
    const float* Wv1 = (const float*)d_in[4];
    const float* Ws1 = (const float*)d_in[5];
    const float* b1  = (const float*)d_in[6];
    const float* Wk2 = (const float*)d_in[7];
    const float* Wq2 = (const float*)d_in[8];
    const float* Wv2 = (const float*)d_in[9];
    const float* Ws2 = (const float*)d_in[10];
    const float* b2  = (const float*)d_in[11];

    const int* src = ei;
    const int* tgt = ei + N_EDGES;

    const size_t nd = (size_t)N_NODES * D;   // 6.4M elements
    short* kb   = (short*)d_ws;              // bf16 K                (nd shorts)
    short* qv   = kb + nd;                   // bf16 QV interleaved   (2*nd)
    short* xb   = qv + 2 * nd;               // bf16 x                (nd)
    short* hb   = xb + nd;                   // bf16 relu(h)          (nd)
    float* agg1 = (float*)(hb + nd);         // fp32 x@Ws1+b1         (nd)
    short* wt   = (short*)(agg1 + nd);       // 8 * 16384 shorts
    int* counts    = (int*)(wt + 8 * W_FRAG_SHORTS);   // N_NODES
    int* done_ctr  = counts + N_NODES;                 // 1 (+1 pad)
    int* off       = counts + N_NODES + 2;             // N_NODES + 1
    int* cursor    = off + N_NODES + 1;                // N_NODES
    int* es        = cursor + N_NODES;                 // N_EDGES
    int* chunk_sum = es + N_EDGES;                     // NCHUNKS
    float* out = (float*)d_out;

    // counts + done_ctr zeroed in one memset
    hipMemsetAsync(counts, 0, (N_NODES + 2) * sizeof(int), stream);
    prep_all<<<PREP_BLOCKS, 256, 0, stream>>>(x, xb,
                                              Wk1, Wq1, Wv1, Ws1, Wk2, Wq2, Wv2, Ws2,
                                              wt, tgt, counts);
    csr_scan<<<NCHUNKS, 256, 0, stream>>>(counts, off, cursor, done_ctr, chunk_sum);

    // Layer 1 (+ fused edge scatter)
    gemm1_scatter<<<NBLK64 + HIST_BLOCKS, 256, 0, stream>>>(
        xb, wt, b1, kb, (unsigned int*)qv, agg1, src, tgt, cursor, es);
    node_agg<true><<<N_NODES / 4, 256, 0, stream>>>(off, es, kb, (const unsigned int*)qv,
                                                    agg1, nullptr, (unsigned int*)hb);

    // Layer 2
    gemm_all<<<NBLK64, 256, 0, stream>>>(hb, wt + 4 * W_FRAG_SHORTS, b2,
                                         kb, (unsigned int*)qv, out);
    node_agg<false><<<N_NODES / 4, 256, 0, stream>>>(off, es, kb, (const unsigned int*)qv,
                                                     out, out, nullptr);
}

// Round 9
// 263.012 us; speedup vs baseline: 1.0235x; 1.0235x over previous
//
#include <hip/hip_runtime.h>

#define N_NODES 50000
#define D 128
#define N_EDGES 400000
#define NCHUNKS ((N_NODES + 255) / 256)   // 196
#define NBLK64 ((N_NODES + 63) / 64)      // 782
#define W_FRAG_SHORTS 16384               // 32 frags * 64 lanes * 8 bf16 per weight

#define MW_BLOCKS  64                     // 8 weights * 8 slot-blocks
#define HIST_BLOCKS ((N_EDGES + 255) / 256)   // 1563
#define PREP_BLOCKS (MW_BLOCKS + HIST_BLOCKS)

typedef short s8v  __attribute__((ext_vector_type(8)));   // 8 bf16 (4 VGPRs)
typedef float f4v  __attribute__((ext_vector_type(4)));   // MFMA accumulator

__device__ __forceinline__ unsigned int f2bf(float f) {
    unsigned int u = __float_as_uint(f);
    u += 0x7FFFu + ((u >> 16) & 1u);
    return u >> 16;
}
__device__ __forceinline__ unsigned int packbf(float a, float b) {
    return (f2bf(b) << 16) | f2bf(a);
}
__device__ __forceinline__ float bflo(unsigned int u) { return __uint_as_float(u << 16); }
__device__ __forceinline__ float bfhi(unsigned int u) { return __uint_as_float(u & 0xFFFF0000u); }
__device__ __forceinline__ float sigm(float x) {
    return __builtin_amdgcn_rcpf(1.f + __expf(-x));   // v_rcp_f32, ~1 ulp
}

// ---------------------------------------------------------------------------
// Prep: [0,MW) weight frags | [MW, ...) tgt histogram. (x cvt removed: gemm1
// converts fp32 x during A-staging — each row is staged exactly once.)
// ---------------------------------------------------------------------------
__global__ __launch_bounds__(256)
void prep_all(const float* __restrict__ W0, const float* __restrict__ W1,
              const float* __restrict__ W2, const float* __restrict__ W3,
              const float* __restrict__ W4, const float* __restrict__ W5,
              const float* __restrict__ W6, const float* __restrict__ W7,
              short* __restrict__ Wt,
              const int* __restrict__ tgt, int* __restrict__ counts)
{
    const int b = blockIdx.x;
    if (b < MW_BLOCKS) {
        const int wsel = b >> 3;
        const float* W = (wsel == 0) ? W0 : (wsel == 1) ? W1 : (wsel == 2) ? W2 :
                         (wsel == 3) ? W3 : (wsel == 4) ? W4 : (wsel == 5) ? W5 :
                         (wsel == 6) ? W6 : W7;
        const int slot = (b & 7) * 256 + threadIdx.x;
        const int frag = slot >> 6;
        const int lane = slot & 63;
        const int n    = (frag >> 2) * 16 + (lane & 15);
        const int kc   = frag & 3;
        const int quad = lane >> 4;
        const int k0   = kc * 32 + quad * 8;
        s8v v;
#pragma unroll
        for (int j = 0; j < 8; ++j)
            v[j] = (short)f2bf(W[(size_t)(k0 + j) * D + n]);
        *(s8v*)(Wt + (size_t)wsel * W_FRAG_SHORTS + (size_t)slot * 8) = v;
    } else {
        const int e = (b - MW_BLOCKS) * 256 + threadIdx.x;
        if (e < N_EDGES) atomicAdd(&counts[tgt[e]], 1);
    }
}

// ---------------------------------------------------------------------------
// Single-kernel CSR offset build (R8-verified).
// ---------------------------------------------------------------------------
__global__ __launch_bounds__(256)
void csr_scan(const int* __restrict__ counts, int* __restrict__ off,
              int* __restrict__ cursor, int* __restrict__ done_ctr,
              int* __restrict__ chunk_sum)
{
    __shared__ int s[256];
    const int b = blockIdx.x, t = threadIdx.x;
    const int i = b * 256 + t;
    const int v = (i < N_NODES) ? counts[i] : 0;
    s[t] = v;
    __syncthreads();
    for (int d = 1; d < 256; d <<= 1) {
        int tt = (t >= d) ? s[t - d] : 0;
        __syncthreads();
        s[t] += tt;
        __syncthreads();
    }
    const int incl = s[t];

    if (t == 255) {
        __hip_atomic_store(&chunk_sum[b], incl, __ATOMIC_RELAXED, __HIP_MEMORY_SCOPE_AGENT);
        __hip_atomic_fetch_add(done_ctr, 1, __ATOMIC_RELEASE, __HIP_MEMORY_SCOPE_AGENT);
    }
    if (t == 0) {
        while (__hip_atomic_load(done_ctr, __ATOMIC_ACQUIRE, __HIP_MEMORY_SCOPE_AGENT) < NCHUNKS)
            __builtin_amdgcn_s_sleep(8);
    }
    __syncthreads();

    const int pv = (t < b) ? __hip_atomic_load(&chunk_sum[t], __ATOMIC_RELAXED,
                                               __HIP_MEMORY_SCOPE_AGENT) : 0;
    __syncthreads();
    s[t] = pv;
    __syncthreads();
    for (int d = 128; d > 0; d >>= 1) {
        if (t < d) s[t] += s[t + d];
        __syncthreads();
    }
    const int base = s[0];

    if (i < N_NODES) {
        const int excl = base + incl - v;
        off[i]    = excl;
        cursor[i] = excl;
    }
    if (b == 0 && t == 0) off[N_NODES] = N_EDGES;
}

// ---------------------------------------------------------------------------
// gemm_tile building blocks
// ---------------------------------------------------------------------------
__device__ __forceinline__
void stage_b(const short* __restrict__ Wf, short* Bs, int tid)
{
#pragma unroll
    for (int j = 0; j < 8; ++j) {
        const int chunk = tid + 256 * j;
        __builtin_amdgcn_global_load_lds(
            (const __attribute__((address_space(1))) unsigned int*)(Wf + chunk * 8),
            (__attribute__((address_space(3))) unsigned int*)(&Bs[(chunk & ~63) * 8]),
            16, 0, 0);
    }
}

__device__ __forceinline__
void mfma_phase(const short* As, const short* Bs, int lane, int wr, int wc,
                f4v acc[2][4])
{
#pragma unroll
    for (int mt = 0; mt < 2; ++mt)
#pragma unroll
        for (int nt = 0; nt < 4; ++nt)
            acc[mt][nt] = (f4v){0.f, 0.f, 0.f, 0.f};
#pragma unroll
    for (int kc = 0; kc < 4; ++kc) {
        const int sl = (lane ^ (kc << 1)) * 8;
        s8v a0 = *(const s8v*)&As[((2 * wr + 0) * 4 + kc) * 512 + sl];
        s8v a1 = *(const s8v*)&As[((2 * wr + 1) * 4 + kc) * 512 + sl];
#pragma unroll
        for (int nt = 0; nt < 4; ++nt) {
            s8v b = *(const s8v*)&Bs[((4 * wc + nt) * 4 + kc) * 512 + lane * 8];
            acc[0][nt] = __builtin_amdgcn_mfma_f32_16x16x32_bf16(a0, b, acc[0][nt], 0, 0, 0);
            acc[1][nt] = __builtin_amdgcn_mfma_f32_16x16x32_bf16(a1, b, acc[1][nt], 0, 0, 0);
        }
    }
}

__device__ __forceinline__
void c_to_lds(float* Cs, int lane, int wr, int wc, const f4v acc[2][4])
{
#pragma unroll
    for (int mt = 0; mt < 2; ++mt) {
        const int r0 = wr * 32 + mt * 16 + (lane >> 4) * 4;
#pragma unroll
        for (int nt = 0; nt < 4; ++nt) {
            const int col = wc * 64 + nt * 16 + (lane & 15);
            const int g = col >> 2, jj = col & 3;
#pragma unroll
            for (int i = 0; i < 4; ++i) {
                const int row = r0 + i;
                const int gs  = g ^ (((row >> 2) & 3) << 2);
                Cs[row * 128 + gs * 4 + jj] = acc[mt][nt][i];
            }
        }
    }
}

// ---------------------------------------------------------------------------
// Fused 4-projection GEMM tile: 64 rows, phases K | QV-joint | S.
// QV epilogue emits full uint4 {q0,v0,q1,v1} stores (full-line, no re-dirty).
// X_FP32: read fp32 X and convert during A-stage (layer 1).
// AGG_BF16: skip/agg output packed bf16 (layer 1); else fp32 (layer 2 -> out).
// ---------------------------------------------------------------------------
template<bool X_FP32, bool AGG_BF16>
__device__ __forceinline__
void gemm_tile(int m0, const float* __restrict__ Xf, const short* __restrict__ Xb,
               const short* __restrict__ WtL, const float* __restrict__ bias,
               short* __restrict__ Kb, unsigned int* __restrict__ QV,
               float* __restrict__ AggF, unsigned int* __restrict__ AggB,
               short* As, short* Bs, float* biasS)
{
    const int tid  = threadIdx.x;
    const int lane = tid & 63;
    const int w    = tid >> 6;
    const int wr   = w & 1;
    const int wc   = w >> 1;

    if (tid < 128) biasS[tid] = bias[tid];

    // ---- Stage A (64 rows x 128 k, bf16) fragment-major, swizzled ----
#pragma unroll
    for (int i = 0; i < 4; ++i) {
        const int m   = (tid >> 4) + 16 * i;
        const int oct = tid & 15;
        const int row = m0 + m;
        s8v v = (s8v){0, 0, 0, 0, 0, 0, 0, 0};
        if (row < N_NODES) {
            if (X_FP32) {
                const float* p = Xf + (size_t)row * D + oct * 8;
                float4 a0 = *(const float4*)p;
                float4 a1 = *(const float4*)(p + 4);
                v[0] = (short)f2bf(a0.x); v[1] = (short)f2bf(a0.y);
                v[2] = (short)f2bf(a0.z); v[3] = (short)f2bf(a0.w);
                v[4] = (short)f2bf(a1.x); v[5] = (short)f2bf(a1.y);
                v[6] = (short)f2bf(a1.z); v[7] = (short)f2bf(a1.w);
            } else {
                v = *(const s8v*)(Xb + (size_t)row * D + oct * 8);
            }
        }
        const int kc = oct >> 2, quad = oct & 3;
        const int frag = (m >> 4) * 4 + kc;
        const int slot = ((m & 15) + 16 * quad) ^ (kc << 1);
        *(s8v*)&As[frag * 512 + slot * 8] = v;
    }

    float* Cs = (float*)Bs;
    f4v acc[2][4];

    // ================= Phase K (sel 0) =================
    __syncthreads();
    stage_b(WtL + 0 * W_FRAG_SHORTS, Bs, tid);
    __syncthreads();
    mfma_phase(As, Bs, lane, wr, wc, acc);
    __syncthreads();
    c_to_lds(Cs, lane, wr, wc, acc);
    __syncthreads();
#pragma unroll
    for (int j = 0; j < 8; ++j) {
        const int c   = tid + 256 * j;
        const int row = c >> 5, gg = c & 31;
        const int gs  = gg ^ (((row >> 2) & 3) << 2);
        const f4v vv  = *(const f4v*)&Cs[row * 128 + gs * 4];
        const int grow = m0 + row;
        if (grow < N_NODES) {
            uint2* kp = (uint2*)((unsigned int*)Kb + (size_t)grow * 64 + gg * 2);
            *kp = make_uint2(packbf(vv[0], vv[1]), packbf(vv[2], vv[3]));
        }
    }

    // ================= Phase QV (sel 1 + 2, joint epilogue) =================
    f4v accV[2][4];
    __syncthreads();                       // Cs readers done
    stage_b(WtL + 1 * W_FRAG_SHORTS, Bs, tid);
    __syncthreads();
    mfma_phase(As, Bs, lane, wr, wc, acc);  // Q
    __syncthreads();
    stage_b(WtL + 2 * W_FRAG_SHORTS, Bs, tid);
    __syncthreads();
    mfma_phase(As, Bs, lane, wr, wc, accV); // V
    __syncthreads();
    c_to_lds(Cs, lane, wr, wc, acc);        // Q roundtrip
    __syncthreads();
    unsigned int qp0[8], qp1[8];
#pragma unroll
    for (int j = 0; j < 8; ++j) {
        const int c   = tid + 256 * j;
        const int row = c >> 5, gg = c & 31;
        const int gs  = gg ^ (((row >> 2) & 3) << 2);
        const f4v vv  = *(const f4v*)&Cs[row * 128 + gs * 4];
        qp0[j] = packbf(vv[0], vv[1]);
        qp1[j] = packbf(vv[2], vv[3]);
    }
    __syncthreads();
    c_to_lds(Cs, lane, wr, wc, accV);       // V roundtrip
    __syncthreads();
#pragma unroll
    for (int j = 0; j < 8; ++j) {
        const int c   = tid + 256 * j;
        const int row = c >> 5, gg = c & 31;
        const int gs  = gg ^ (((row >> 2) & 3) << 2);
        const f4v vv  = *(const f4v*)&Cs[row * 128 + gs * 4];
        const int grow = m0 + row;
        if (grow < N_NODES) {
            uint4* qvp = (uint4*)(QV + (size_t)grow * 128 + gg * 4);
            *qvp = make_uint4(qp0[j], packbf(vv[0], vv[1]),
                              qp1[j], packbf(vv[2], vv[3]));
        }
    }

    // ================= Phase S (sel 3, skip + bias) =================
    __syncthreads();
    stage_b(WtL + 3 * W_FRAG_SHORTS, Bs, tid);
    __syncthreads();
    mfma_phase(As, Bs, lane, wr, wc, acc);
    __syncthreads();
    c_to_lds(Cs, lane, wr, wc, acc);
    __syncthreads();
#pragma unroll
    for (int j = 0; j < 8; ++j) {
        const int c   = tid + 256 * j;
        const int row = c >> 5, gg = c & 31;
        const int gs  = gg ^ (((row >> 2) & 3) << 2);
        const f4v vv  = *(const f4v*)&Cs[row * 128 + gs * 4];
        const int grow = m0 + row;
        if (grow >= N_NODES) continue;
        const float4 bv = *(const float4*)&biasS[gg * 4];
        const float o0 = vv[0] + bv.x, o1 = vv[1] + bv.y;
        const float o2 = vv[2] + bv.z, o3 = vv[3] + bv.w;
        if (AGG_BF16) {
            uint2* ap = (uint2*)(AggB + (size_t)grow * 64 + gg * 2);
            *ap = make_uint2(packbf(o0, o1), packbf(o2, o3));
        } else {
            *(float4*)&AggF[(size_t)grow * D + gg * 4] = make_float4(o0, o1, o2, o3);
        }
    }
}

// ---------------------------------------------------------------------------
// Layer-1 GEMM (fp32 x input, bf16 agg out) + fused edge scatter blocks.
// ---------------------------------------------------------------------------
__global__ __launch_bounds__(256)
void gemm1_scatter(const float* __restrict__ X, const short* __restrict__ WtL,
                   const float* __restrict__ bias,
                   short* __restrict__ Kb, unsigned int* __restrict__ QV,
                   unsigned int* __restrict__ AggB,
                   const int* __restrict__ src, const int* __restrict__ tgt,
                   int* __restrict__ cursor, int* __restrict__ es)
{
    __shared__ __align__(16) short As[8192];    // 16 KB
    __shared__ __align__(16) short Bs[16384];   // 32 KB (doubles as Cs fp32)
    __shared__ __align__(16) float biasS[128];

    if (blockIdx.x < NBLK64) {
        gemm_tile<true, true>(blockIdx.x * 64, X, nullptr, WtL, bias,
                              Kb, QV, nullptr, AggB, As, Bs, biasS);
    } else {
        const int e = (blockIdx.x - NBLK64) * 256 + threadIdx.x;
        if (e < N_EDGES) {
            int pos = atomicAdd(&cursor[tgt[e]], 1);
            es[pos] = src[e];
        }
    }
}

// Layer-2 GEMM (bf16 relu(h) input, fp32 agg -> d_out).
__global__ __launch_bounds__(256)
void gemm2(const short* __restrict__ Hb, const short* __restrict__ WtL,
           const float* __restrict__ bias,
           short* __restrict__ Kb, unsigned int* __restrict__ QV,
           float* __restrict__ AggF)
{
    __shared__ __align__(16) short As[8192];
    __shared__ __align__(16) short Bs[16384];
    __shared__ __align__(16) float biasS[128];
    gemm_tile<false, false>(blockIdx.x * 64, nullptr, Hb, WtL, bias,
                            Kb, QV, AggF, nullptr, As, Bs, biasS);
}

// ---------------------------------------------------------------------------
// Atomic-free per-node aggregation. One wave per node. 8-wide gather stage:
// one lane-parallel es load + readlane (8 uint2 gathers in flight).
// FIRST: Skip = bf16 agg1; out = bf16 relu -> Hb. Else: Skip = fp32 (d_out RMW).
// ---------------------------------------------------------------------------
template<bool FIRST>
__global__ __launch_bounds__(256)
void node_agg(const int* __restrict__ off, const int* __restrict__ es,
              const short* __restrict__ K, const unsigned int* __restrict__ QV,
              const void* __restrict__ Skip, float* __restrict__ OutF,
              unsigned int* __restrict__ Hb)
{
    const int lane = threadIdx.x & 63;
    const int t    = __builtin_amdgcn_readfirstlane(blockIdx.x * 4 + (threadIdx.x >> 6));

    const unsigned int ku = ((const unsigned int*)K)[(size_t)t * 64 + lane];
    const float kx = bflo(ku), ky = bfhi(ku);

    float skx, sky;
    if (FIRST) {
        const unsigned int su = ((const unsigned int*)Skip)[(size_t)t * 64 + lane];
        skx = bflo(su); sky = bfhi(su);
    } else {
        const float2 s2 = ((const float2*)Skip)[(size_t)t * 64 + lane];
        skx = s2.x; sky = s2.y;
    }

    float ax = 0.f, ay = 0.f, bx = 0.f, by = 0.f;
    const int e0 = __builtin_amdgcn_readfirstlane(off[t]);
    const int e1 = __builtin_amdgcn_readfirstlane(off[t + 1]);

    int e = e0;
    for (; e + 8 <= e1; e += 8) {
        const int sv = es[e + (lane & 7)];
        uint2 g[8];
#pragma unroll
        for (int u = 0; u < 8; ++u) {
            const int s = __builtin_amdgcn_readlane(sv, u);
            g[u] = ((const uint2*)(QV + (size_t)s * 128))[lane];
        }
#pragma unroll
        for (int u = 0; u < 8; ++u) {
            if (u & 1) {
                bx += bflo(g[u].y) * sigm(kx + bflo(g[u].x));
                by += bfhi(g[u].y) * sigm(ky + bfhi(g[u].x));
            } else {
                ax += bflo(g[u].y) * sigm(kx + bflo(g[u].x));
                ay += bfhi(g[u].y) * sigm(ky + bfhi(g[u].x));
            }
        }
    }
    if (e + 4 <= e1) {
        const int sv = es[e + (lane & 3)];
        uint2 g[4];
#pragma unroll
        for (int u = 0; u < 4; ++u) {
            const int s = __builtin_amdgcn_readlane(sv, u);
            g[u] = ((const uint2*)(QV + (size_t)s * 128))[lane];
        }
#pragma unroll
        for (int u = 0; u < 4; ++u) {
            if (u & 1) {
                bx += bflo(g[u].y) * sigm(kx + bflo(g[u].x));
                by += bfhi(g[u].y) * sigm(ky + bfhi(g[u].x));
            } else {
                ax += bflo(g[u].y) * sigm(kx + bflo(g[u].x));
                ay += bfhi(g[u].y) * sigm(ky + bfhi(g[u].x));
            }
        }
        e += 4;
    }
    for (; e < e1; ++e) {
        const int s0 = __builtin_amdgcn_readfirstlane(es[e]);
        const uint2 g0 = ((const uint2*)(QV + (size_t)s0 * 128))[lane];
        ax += bflo(g0.y) * sigm(kx + bflo(g0.x));
        ay += bfhi(g0.y) * sigm(ky + bfhi(g0.x));
    }

    const float rx = skx + ax + bx;
    const float ry = sky + ay + by;

    if (FIRST) {
        Hb[(size_t)t * 64 + lane] = packbf(fmaxf(rx, 0.f), fmaxf(ry, 0.f));
    } else {
        ((float2*)OutF)[(size_t)t * 64 + lane] = make_float2(rx, ry);
    }
}

extern "C" void kernel_launch(void* const* d_in, const int* in_sizes, int n_in,
                              void* d_out, int out_size, void* d_ws, size_t ws_size,
                              hipStream_t stream)
{
    const float* x   = (const float*)d_in[0];
    const int*   ei  = (const int*)d_in[1];
    const float* Wk1 = (const float*)d_in[2];
    const float* Wq1 = (const float*)d_in[3];
    const float* Wv1 = (const float*)d_in[4];
    const float* Ws1 = (const float*)d_in[5];
    const float* b1  = (const float*)d_in[6];
    const float* Wk2 = (const float*)d_in[7];
    const float* Wq2 = (const float*)d_in[8];
    const float* Wv2 = (const float*)d_in[9];
    const float* Ws2 = (const float*)d_in[10];
    const float* b2  = (const float*)d_in[11];

    const int* src = ei;
    const int* tgt = ei + N_EDGES;

    const size_t nd = (size_t)N_NODES * D;   // 6.4M elements
    short* kb   = (short*)d_ws;              // bf16 K                (nd shorts)
    short* qv   = kb + nd;                   // bf16 QV interleaved   (2*nd)
    short* hb   = qv + 2 * nd;               // bf16 relu(h)          (nd)
    short* ag1  = hb + nd;                   // bf16 x@Ws1+b1         (nd)
    short* wt   = ag1 + nd;                  // 8 * 16384 shorts
    int* counts    = (int*)(wt + 8 * W_FRAG_SHORTS);   // N_NODES
    int* done_ctr  = counts + N_NODES;                 // 1 (+1 pad)
    int* off       = counts + N_NODES + 2;             // N_NODES + 1
    int* cursor    = off + N_NODES + 1;                // N_NODES
    int* es        = cursor + N_NODES;                 // N_EDGES
    int* chunk_sum = es + N_EDGES;                     // NCHUNKS
    float* out = (float*)d_out;

    hipMemsetAsync(counts, 0, (N_NODES + 2) * sizeof(int), stream);
    prep_all<<<PREP_BLOCKS, 256, 0, stream>>>(Wk1, Wq1, Wv1, Ws1, Wk2, Wq2, Wv2, Ws2,
                                              wt, tgt, counts);
    csr_scan<<<NCHUNKS, 256, 0, stream>>>(counts, off, cursor, done_ctr, chunk_sum);

    // Layer 1 (+ fused edge scatter)
    gemm1_scatter<<<NBLK64 + HIST_BLOCKS, 256, 0, stream>>>(
        x, wt, b1, kb, (unsigned int*)qv, (unsigned int*)ag1, src, tgt, cursor, es);
    node_agg<true><<<N_NODES / 4, 256, 0, stream>>>(off, es, kb, (const unsigned int*)qv,
                                                    ag1, nullptr, (unsigned int*)hb);

    // Layer 2
    gemm2<<<NBLK64, 256, 0, stream>>>(hb, wt + 4 * W_FRAG_SHORTS, b2,
                                      kb, (unsigned int*)qv, out);
    node_agg<false><<<N_NODES / 4, 256, 0, stream>>>(off, es, kb, (const unsigned int*)qv,
                                                     out, out, nullptr);
}